// Round 10
// baseline (221.719 us; speedup 1.0000x reference)
//
#include <hip/hip_runtime.h>
#include <hip/hip_bf16.h>
#include <cstdint>
#include <cstddef>

// Problem constants (DialogueRNNCell: B=4096, T=128, P=2, all feature dims 256)
#define B_N   4096
#define T_N   128
#define P_N   2
#define D     256
#define NG    768                  // 3*D gate width
#define BD    (B_N * D)            // elements per g_hist time slice
#define AGRID 1024                 // attn_fused grid
#define AGSIZE (AGRID * 256)

typedef __attribute__((ext_vector_type(4))) float f32x4;
typedef __attribute__((ext_vector_type(8))) short bf16x8;
typedef __attribute__((ext_vector_type(8))) unsigned short ushort8;

__device__ __forceinline__ unsigned short f2bf(float f) {
    __hip_bfloat16 h = __float2bfloat16(f);
    return *reinterpret_cast<unsigned short*>(&h);
}

// ---------------------------------------------------------------------------
// Params structs
// ---------------------------------------------------------------------------
struct AttnParams {
    const float *U, *g_hist, *q0, *e0;
    const int   *qm;
    const float *wg_ih, *wg_hh, *wp_ih, *wp_hh, *we_ih, *we_hh;
    const float *attn_w;
    float *a_out;
    unsigned short *U_bf, *e0_bf, *glast_bf, *q0sel_bf, *c_bf;
    unsigned short *wgih_bf, *wpih_bf, *wghh_bf, *wphh_bf, *weih_bf, *wehh_bf;
};

struct GPParams {
    const unsigned short *U_bf, *q0sel_bf, *glast_bf, *c_bf;
    const unsigned short *wgih_bf, *wghh_bf, *wpih_bf, *wphh_bf;
    const float *bg_ih, *bg_hh, *bp_ih, *bp_hh;
    const float *g_last, *q0;
    const int *qm;
    float *g_out, *q_out;
    unsigned short *qssel_bf;
};

// ---------------------------------------------------------------------------
// f32 -> bf16 grid-stride conversion, 8 elems per iteration
// ---------------------------------------------------------------------------
__device__ __forceinline__ void cvt8(
    const float* __restrict__ src, unsigned short* __restrict__ dst,
    int n8, int gtid)
{
    for (int i = gtid; i < n8; i += AGSIZE) {
        const float4* s = reinterpret_cast<const float4*>(src + i * 8);
        const float4 v0 = s[0], v1 = s[1];
        ushort8 o = { f2bf(v0.x), f2bf(v0.y), f2bf(v0.z), f2bf(v0.w),
                      f2bf(v1.x), f2bf(v1.y), f2bf(v1.z), f2bf(v1.w) };
        *reinterpret_cast<ushort8*>(dst + i * 8) = o;
    }
}

// ---------------------------------------------------------------------------
// Kernel 1: cvt + gather prelude (grid-stride) then attention.
// Attn: one wave per b, one pass, online softmax. c_ emitted in bf16.
// Kernel completion = barrier before the GRUs.
// ---------------------------------------------------------------------------
__global__ __launch_bounds__(256) void attn_fused(AttnParams p)
{
    const int tid  = threadIdx.x;
    const int lane = tid & 63;
    const int wid  = tid >> 6;
    const int gtid = blockIdx.x * 256 + tid;

    const float* g_last = p.g_hist + (size_t)(T_N - 1) * BD;

    // ---- prelude: conversions + gather (grid-stride over whole grid) ----
    cvt8(p.wg_ih, p.wgih_bf, NG * 512 / 8, gtid);
    cvt8(p.wg_hh, p.wghh_bf, NG * 256 / 8, gtid);
    cvt8(p.wp_ih, p.wpih_bf, NG * 512 / 8, gtid);
    cvt8(p.wp_hh, p.wphh_bf, NG * 256 / 8, gtid);
    cvt8(p.we_ih, p.weih_bf, NG * 256 / 8, gtid);
    cvt8(p.we_hh, p.wehh_bf, NG * 256 / 8, gtid);
    cvt8(p.U,     p.U_bf,     B_N * D / 8, gtid);
    cvt8(p.e0,    p.e0_bf,    B_N * D / 8, gtid);
    cvt8(g_last,  p.glast_bf, B_N * D / 8, gtid);
    for (int i = gtid; i < B_N * D / 4; i += AGSIZE) {
        const int row = i >> 6;
        const int j   = (i & 63) * 4;
        const float4 v = *reinterpret_cast<const float4*>(
            p.q0 + ((size_t)row * P_N + p.qm[row]) * D + j);
        ushort4 bv = { f2bf(v.x), f2bf(v.y), f2bf(v.z), f2bf(v.w) };
        *reinterpret_cast<ushort4*>(p.q0sel_bf + (size_t)row * D + j) = bv;
    }

    // ---- attention: b = blockIdx.x*4 + wid ----
    const int b = blockIdx.x * 4 + wid;

    const float4 w4 = *reinterpret_cast<const float4*>(p.attn_w + lane * 4);
    const float* gbase = p.g_hist + (size_t)b * D + lane * 4;

    float  m = -INFINITY, l = 0.f;
    float4 acc = {0.f, 0.f, 0.f, 0.f};
    float  s0 = 0.f, s1 = 0.f;   // per-lane stash of raw scores (t&63==lane)

    auto step = [&](int t, const float4& g) {
        float dot = g.x * w4.x + g.y * w4.y + g.z * w4.z + g.w * w4.w;
        #pragma unroll
        for (int off = 32; off >= 1; off >>= 1)
            dot += __shfl_xor(dot, off, 64);
        const float mn   = fmaxf(m, dot);
        const float corr = __expf(m - mn);     // t==0: exp(-inf)=0 zeroes state
        const float pr   = __expf(dot - mn);
        l = l * corr + pr;
        acc.x = fmaf(pr, g.x, acc.x * corr);
        acc.y = fmaf(pr, g.y, acc.y * corr);
        acc.z = fmaf(pr, g.z, acc.z * corr);
        acc.w = fmaf(pr, g.w, acc.w * corr);
        m = mn;
        if ((t & 63) == lane) { if (t & 64) s1 = dot; else s0 = dot; }
    };

    for (int t = 0; t < T_N; t += 2) {
        const float4 g0 = *reinterpret_cast<const float4*>(gbase + (size_t)t * BD);
        const float4 g1 = *reinterpret_cast<const float4*>(gbase + (size_t)(t + 1) * BD);
        step(t, g0);
        step(t + 1, g1);
    }

    const float rl = 1.f / l;
    ushort4 cv = { f2bf(acc.x * rl), f2bf(acc.y * rl),
                   f2bf(acc.z * rl), f2bf(acc.w * rl) };
    *reinterpret_cast<ushort4*>(p.c_bf + (size_t)b * D + lane * 4) = cv;
    p.a_out[(size_t)b * T_N + lane]      = __expf(s0 - m) * rl;
    p.a_out[(size_t)b * T_N + 64 + lane] = __expf(s1 - m) * rl;
}

// ---------------------------------------------------------------------------
// Barrier-free per-wave register GRU GEMM + fused gate epilogue.
// Each wave: 16 A-rows x 96 gate-cols (c0 slice of 32 output cols x 3 gates).
// Per K-step: a + b[0..5] fragments loaded DIRECTLY global->VGPR as 16B
// contiguous loads (lane: row0+fr, col kt + s*8 — coalesced); 6 MFMAs.
// Depth-3 rolling prefetch, 4 buffers, fully unrolled (indices compile-time).
// No LDS, no barriers; MFMA order per (row,col) identical to the staged
// version -> bit-identical results. kcolA/kcolW separate (round-3 lesson).
//   MODE 0: out_f32[row*256+col] = val   (h = hsrc[row*256+col])
//   MODE 1: party — h = q0[row,qm,col]; writes q_out both slots + qs bf16
// ---------------------------------------------------------------------------
template<int MODE, int NI, int LDWI>
__device__ __forceinline__ void gru_wave(
    int row0, int c0, int lane,
    const unsigned short* __restrict__ A0,
    const unsigned short* __restrict__ A1,
    const unsigned short* __restrict__ Wi, const float* __restrict__ bi,
    const unsigned short* __restrict__ Ah,
    const unsigned short* __restrict__ Wh, const float* __restrict__ bh,
    const float* __restrict__ hsrc, const int* __restrict__ qm,
    float* __restrict__ out_f32, unsigned short* __restrict__ out_bf)
{
    constexpr int NT = NI + 8;

    const int fr = lane & 15;        // fragment row (A) / gate-row (W)
    const int s  = lane >> 4;        // k-slot 0..3

    f32x4 accI[6] = {};
    f32x4 accH[6] = {};

    bf16x8 a[4];
    bf16x8 b[4][6];

    auto loadstep = [&](int st, int buf) {
        const unsigned short* Apart;
        const unsigned short* W;
        int kcolA, kcolW, ldw;
        if (st < NI) {
            const int kt = st * 32;
            Apart = (kt < D) ? A0 : A1;
            kcolA = kt & (D - 1);
            kcolW = kt;
            W     = Wi;
            ldw   = LDWI;
        } else {
            const int kt = (st - NI) * 32;
            Apart = Ah; kcolA = kt; kcolW = kt; W = Wh; ldw = D;
        }
        a[buf] = *reinterpret_cast<const bf16x8*>(
            Apart + (size_t)(row0 + fr) * D + kcolA + s * 8);
        #pragma unroll
        for (int j = 0; j < 6; ++j) {
            const int wrow = (j >> 1) * 256 + c0 + (j & 1) * 16 + fr;
            b[buf][j] = *reinterpret_cast<const bf16x8*>(
                W + (size_t)wrow * ldw + kcolW + s * 8);
        }
    };

    loadstep(0, 0);
    loadstep(1, 1);
    loadstep(2, 2);

    #pragma unroll
    for (int st = 0; st < NT; ++st) {
        if (st + 3 < NT) loadstep(st + 3, (st + 3) & 3);
        const int buf = st & 3;
        if (st < NI) {
            #pragma unroll
            for (int j = 0; j < 6; ++j)
                accI[j] = __builtin_amdgcn_mfma_f32_16x16x32_bf16(
                    a[buf], b[buf][j], accI[j], 0, 0, 0);
        } else {
            #pragma unroll
            for (int j = 0; j < 6; ++j)
                accH[j] = __builtin_amdgcn_mfma_f32_16x16x32_bf16(
                    a[buf], b[buf][j], accH[j], 0, 0, 0);
        }
    }

    // ---- gate epilogue (thread-local: r/z/n fragments share (row,col)) ----
    const int cr = s * 4;
    const int cc = fr;
    #pragma unroll
    for (int jj = 0; jj < 2; ++jj) {
        const int col = c0 + jj * 16 + cc;
        const float bir = bi[col],       bhr = bh[col];
        const float biz = bi[col + 256], bhz = bh[col + 256];
        const float bin = bi[col + 512], bhn = bh[col + 512];
        #pragma unroll
        for (int q = 0; q < 4; ++q) {
            const int row = row0 + cr + q;
            const float ir  = accI[jj][q]     + bir;
            const float hr  = accH[jj][q]     + bhr;
            const float iz  = accI[jj + 2][q] + biz;
            const float hz  = accH[jj + 2][q] + bhz;
            const float in_ = accI[jj + 4][q] + bin;
            const float hn  = accH[jj + 4][q] + bhn;
            const float rg = 1.f / (1.f + __expf(-(ir + hr)));
            const float zg = 1.f / (1.f + __expf(-(iz + hz)));
            const float ng = tanhf(in_ + rg * hn);
            if (MODE == 1) {
                const int p = qm[row];
                const float hv  = hsrc[(size_t)row * 512 + (size_t)p * 256 + col];
                const float ov  = hsrc[(size_t)row * 512 + (size_t)(1 - p) * 256 + col];
                const float val = (1.f - zg) * ng + zg * hv;
                out_f32[(size_t)row * 512 + (size_t)p * 256 + col]       = val;
                out_f32[(size_t)row * 512 + (size_t)(1 - p) * 256 + col] = ov;
                out_bf[(size_t)row * 256 + col] = f2bf(val);
            } else {
                const float hv  = hsrc[(size_t)row * 256 + col];
                const float val = (1.f - zg) * ng + zg * hv;
                out_f32[(size_t)row * 256 + col] = val;
            }
        }
    }
}

// ---------------------------------------------------------------------------
// Kernel 2: global GRU (blocks 0..511) | party GRU (blocks 512..1023).
// 4 independent waves per block; wave tile 16 rows x 96 gate-cols.
// ---------------------------------------------------------------------------
__global__ __launch_bounds__(256) void gp_gru(GPParams p)
{
    const int tid  = threadIdx.x;
    const int lane = tid & 63;
    const int wid  = tid >> 6;
    const int bid  = blockIdx.x;

    if (bid < 512) {
        const int wg   = bid * 4 + wid;          // 0..2047
        const int row0 = (wg & 255) * 16;
        const int c0   = (wg >> 8) * 32;
        gru_wave<0, 16, 512>(row0, c0, lane,
            p.U_bf, p.q0sel_bf, p.wgih_bf, p.bg_ih,
            p.glast_bf, p.wghh_bf, p.bg_hh,
            p.g_last, nullptr, p.g_out, nullptr);
    } else {
        const int wg   = (bid - 512) * 4 + wid;
        const int row0 = (wg & 255) * 16;
        const int c0   = (wg >> 8) * 32;
        gru_wave<1, 16, 512>(row0, c0, lane,
            p.U_bf, p.c_bf, p.wpih_bf, p.bp_ih,
            p.q0sel_bf, p.wphh_bf, p.bp_hh,
            p.q0, p.qm, p.q_out, p.qssel_bf);
    }
}

// ---------------------------------------------------------------------------
// Kernel 3: emotion GRU (512 blocks).
// ---------------------------------------------------------------------------
__global__ __launch_bounds__(256) void e_gru(
    const unsigned short* __restrict__ qssel_bf,
    const unsigned short* __restrict__ weih_bf, const float* __restrict__ be_ih,
    const unsigned short* __restrict__ e0_bf,
    const unsigned short* __restrict__ wehh_bf, const float* __restrict__ be_hh,
    const float* __restrict__ e0, float* __restrict__ e_out)
{
    const int tid  = threadIdx.x;
    const int lane = tid & 63;
    const int wid  = tid >> 6;
    const int wg   = blockIdx.x * 4 + wid;       // 0..2047
    const int row0 = (wg & 255) * 16;
    const int c0   = (wg >> 8) * 32;
    gru_wave<0, 8, 256>(row0, c0, lane,
        qssel_bf, nullptr, weih_bf, be_ih,
        e0_bf, wehh_bf, be_hh,
        e0, nullptr, e_out, nullptr);
}

// ---------------------------------------------------------------------------
extern "C" void kernel_launch(void* const* d_in, const int* in_sizes, int n_in,
                              void* d_out, int out_size, void* d_ws, size_t ws_size,
                              hipStream_t stream)
{
    const float* U      = (const float*)d_in[0];
    const int*   qm     = (const int*)  d_in[1];
    const float* g_hist = (const float*)d_in[2];
    const float* q0     = (const float*)d_in[3];
    const float* e0     = (const float*)d_in[4];
    const float* wg_ih  = (const float*)d_in[5];
    const float* wg_hh  = (const float*)d_in[6];
    const float* bg_ih  = (const float*)d_in[7];
    const float* bg_hh  = (const float*)d_in[8];
    const float* wp_ih  = (const float*)d_in[9];
    const float* wp_hh  = (const float*)d_in[10];
    const float* bp_ih  = (const float*)d_in[11];
    const float* bp_hh  = (const float*)d_in[12];
    const float* we_ih  = (const float*)d_in[13];
    const float* we_hh  = (const float*)d_in[14];
    const float* be_ih  = (const float*)d_in[15];
    const float* be_hh  = (const float*)d_in[16];
    const float* attn_w = (const float*)d_in[17];

    float* out   = (float*)d_out;
    float* g_out = out;                       // [B, 256]
    float* q_out = out + 1048576;             // [B, 2, 256]
    float* e_out = out + 3145728;             // [B, 256]
    float* a_out = out + 4194304;             // [B, 1, 128]

    unsigned short* bf = (unsigned short*)d_ws;
    unsigned short* U_bf     = bf;
    unsigned short* e0_bf    = bf + 1048576;
    unsigned short* glast_bf = bf + 2097152;
    unsigned short* q0sel_bf = bf + 3145728;
    unsigned short* c_bf     = bf + 4194304;
    unsigned short* qssel_bf = bf + 5242880;
    unsigned short* wgih_bf  = bf + 6291456;
    unsigned short* wpih_bf  = bf + 6684672;
    unsigned short* wghh_bf  = bf + 7077888;
    unsigned short* wphh_bf  = bf + 7274496;
    unsigned short* weih_bf  = bf + 7471104;
    unsigned short* wehh_bf  = bf + 7667712;       // end 7864320 elems (15.7 MB)

    const float* g_last = g_hist + (size_t)(T_N - 1) * BD;

    AttnParams ap;
    ap.U = U; ap.g_hist = g_hist; ap.q0 = q0; ap.e0 = e0; ap.qm = qm;
    ap.wg_ih = wg_ih; ap.wg_hh = wg_hh; ap.wp_ih = wp_ih; ap.wp_hh = wp_hh;
    ap.we_ih = we_ih; ap.we_hh = we_hh; ap.attn_w = attn_w;
    ap.a_out = a_out;
    ap.U_bf = U_bf; ap.e0_bf = e0_bf; ap.glast_bf = glast_bf;
    ap.q0sel_bf = q0sel_bf; ap.c_bf = c_bf;
    ap.wgih_bf = wgih_bf; ap.wpih_bf = wpih_bf; ap.wghh_bf = wghh_bf;
    ap.wphh_bf = wphh_bf; ap.weih_bf = weih_bf; ap.wehh_bf = wehh_bf;

    GPParams gp;
    gp.U_bf = U_bf; gp.q0sel_bf = q0sel_bf; gp.glast_bf = glast_bf;
    gp.c_bf = c_bf;
    gp.wgih_bf = wgih_bf; gp.wghh_bf = wghh_bf;
    gp.wpih_bf = wpih_bf; gp.wphh_bf = wphh_bf;
    gp.bg_ih = bg_ih; gp.bg_hh = bg_hh; gp.bp_ih = bp_ih; gp.bp_hh = bp_hh;
    gp.g_last = g_last; gp.q0 = q0; gp.qm = qm;
    gp.g_out = g_out; gp.q_out = q_out; gp.qssel_bf = qssel_bf;

    const dim3 blk(256);
    attn_fused<<<AGRID, blk, 0, stream>>>(ap);
    gp_gru<<<1024, blk, 0, stream>>>(gp);
    e_gru<<<512, blk, 0, stream>>>(
        qssel_bf, weih_bf, be_ih, e0_bf, wehh_bf, be_hh, e0, e_out);
}

// Round 12
// 215.199 us; speedup vs baseline: 1.0303x; 1.0303x over previous
//
#include <hip/hip_runtime.h>
#include <hip/hip_bf16.h>
#include <cstdint>
#include <cstddef>

// Problem constants (DialogueRNNCell: B=4096, T=128, P=2, all feature dims 256)
#define B_N   4096
#define T_N   128
#define P_N   2
#define D     256
#define NG    768                  // 3*D gate width
#define BD    (B_N * D)            // elements per g_hist time slice
#define CGRID 1024                 // cvt_all grid
#define CGSIZE (CGRID * 256)

typedef __attribute__((ext_vector_type(4))) float f32x4;
typedef __attribute__((ext_vector_type(8))) short bf16x8;
typedef __attribute__((ext_vector_type(8))) unsigned short ushort8;

__device__ __forceinline__ unsigned short f2bf(float f) {
    __hip_bfloat16 h = __float2bfloat16(f);
    return *reinterpret_cast<unsigned short*>(&h);
}

// ---------------------------------------------------------------------------
// Params structs
// ---------------------------------------------------------------------------
struct CvtParams {
    const float *U, *e0, *g_last, *q0;
    const int   *qm;
    const float *wg_ih, *wg_hh, *wp_ih, *wp_hh, *we_ih, *we_hh;
    unsigned short *U_bf, *e0_bf, *glast_bf, *q0sel_bf;
    unsigned short *wgih_bf, *wpih_bf, *wghh_bf, *wphh_bf, *weih_bf, *wehh_bf;
};

struct AttnGParams {
    const float *g_hist, *attn_w, *g_last;
    float *a_out, *g_out;
    unsigned short *c_bf;
    const unsigned short *U_bf, *q0sel_bf, *glast_bf, *wgih_bf, *wghh_bf;
    const float *bg_ih, *bg_hh;
};

// ---------------------------------------------------------------------------
// f32 -> bf16 grid-stride conversion, 8 elems per iteration
// ---------------------------------------------------------------------------
__device__ __forceinline__ void cvt8(
    const float* __restrict__ src, unsigned short* __restrict__ dst,
    int n8, int gtid)
{
    for (int i = gtid; i < n8; i += CGSIZE) {
        const float4* s = reinterpret_cast<const float4*>(src + i * 8);
        const float4 v0 = s[0], v1 = s[1];
        ushort8 o = { f2bf(v0.x), f2bf(v0.y), f2bf(v0.z), f2bf(v0.w),
                      f2bf(v1.x), f2bf(v1.y), f2bf(v1.z), f2bf(v1.w) };
        *reinterpret_cast<ushort8*>(dst + i * 8) = o;
    }
}

// ---------------------------------------------------------------------------
// Kernel 1: all f32 -> bf16 staging (weights, U, e0, g_last, q0sel gather)
// ---------------------------------------------------------------------------
__global__ __launch_bounds__(256) void cvt_all(CvtParams p)
{
    const int gtid = blockIdx.x * 256 + threadIdx.x;
    cvt8(p.wg_ih, p.wgih_bf, NG * 512 / 8, gtid);
    cvt8(p.wg_hh, p.wghh_bf, NG * 256 / 8, gtid);
    cvt8(p.wp_ih, p.wpih_bf, NG * 512 / 8, gtid);
    cvt8(p.wp_hh, p.wphh_bf, NG * 256 / 8, gtid);
    cvt8(p.we_ih, p.weih_bf, NG * 256 / 8, gtid);
    cvt8(p.we_hh, p.wehh_bf, NG * 256 / 8, gtid);
    cvt8(p.U,      p.U_bf,     B_N * D / 8, gtid);
    cvt8(p.e0,     p.e0_bf,    B_N * D / 8, gtid);
    cvt8(p.g_last, p.glast_bf, B_N * D / 8, gtid);
    for (int i = gtid; i < B_N * D / 4; i += CGSIZE) {
        const int row = i >> 6;
        const int j   = (i & 63) * 4;
        const float4 v = *reinterpret_cast<const float4*>(
            p.q0 + ((size_t)row * P_N + p.qm[row]) * D + j);
        ushort4 bv = { f2bf(v.x), f2bf(v.y), f2bf(v.z), f2bf(v.w) };
        *reinterpret_cast<ushort4*>(p.q0sel_bf + (size_t)row * D + j) = bv;
    }
}

// ---------------------------------------------------------------------------
// SAFE GRU tile body (round-4 proven; passed at 184.5 µs):
// 128 A-rows x 32 gate-cols, BK=32, single LDS buffer (16 KB),
// __syncthreads() only — NO inline asm, NO counted vmcnt. Robust to any
// codegen context (used inside the mixed-role kernel).
// W-tile rows {c0,c0+256,c0+512} padded 96->128 by duplication.
// 16B-slot XOR swizzle phys = s ^ ((row>>1)&3) on SOURCE + ds_read side.
// kcolA / kcolW SEPARATE (round-3 lesson).
// ---------------------------------------------------------------------------
template<int NI, int LDWI>
__device__ __forceinline__ void gru_sync128(
    int r0, int c0, unsigned short* As, unsigned short* Ws, int tid,
    const unsigned short* __restrict__ A0,
    const unsigned short* __restrict__ A1,
    const unsigned short* __restrict__ Wi, const float* __restrict__ bi,
    const unsigned short* __restrict__ Ah,
    const unsigned short* __restrict__ Wh, const float* __restrict__ bh,
    const float* __restrict__ hsrc, float* __restrict__ out_f32)
{
    const int lane = tid & 63;
    const int wid  = tid >> 6;
    const int st_row = lane >> 2;       // 0..15
    const int st_p   = lane & 3;        // physical 16B slot

    f32x4 accI[2][6] = {};
    f32x4 accH[2][6] = {};

    auto kstep = [&](const unsigned short* Apart, int kcolA, int kcolW,
                     const unsigned short* W, int ldw, f32x4 (&acc)[2][6]) {
        #pragma unroll
        for (int c = 0; c < 2; ++c) {
            const int row  = wid * 32 + c * 16 + st_row;          // 0..127
            const int scol = (st_p ^ ((row >> 1) & 3)) * 8;       // swizzled src
            __builtin_amdgcn_global_load_lds(
                (const __attribute__((address_space(1))) void*)
                    (Apart + (size_t)(r0 + row) * D + kcolA + scol),
                (__attribute__((address_space(3))) void*)
                    (As + wid * 1024 + c * 512), 16, 0, 0);
            int grp = row >> 5; if (grp == 3) grp = 2;            // pad rows dup
            const int wrow = grp * 256 + c0 + (row & 31);
            __builtin_amdgcn_global_load_lds(
                (const __attribute__((address_space(1))) void*)
                    (W + (size_t)wrow * ldw + kcolW + scol),
                (__attribute__((address_space(3))) void*)
                    (Ws + wid * 1024 + c * 512), 16, 0, 0);
        }
        __syncthreads();

        const int s  = lane >> 4;        // logical k-slot 0..3
        const int fr = lane & 15;
        bf16x8 a[2], b[6];
        #pragma unroll
        for (int m = 0; m < 2; ++m) {
            const int row = wid * 32 + m * 16 + fr;
            const int ph  = s ^ ((row >> 1) & 3);
            a[m] = *reinterpret_cast<const bf16x8*>(&As[row * 32 + ph * 8]);
        }
        #pragma unroll
        for (int j = 0; j < 6; ++j) {
            const int row = j * 16 + fr;
            const int ph  = s ^ ((row >> 1) & 3);
            b[j] = *reinterpret_cast<const bf16x8*>(&Ws[row * 32 + ph * 8]);
        }
        #pragma unroll
        for (int m = 0; m < 2; ++m)
            #pragma unroll
            for (int j = 0; j < 6; ++j)
                acc[m][j] = __builtin_amdgcn_mfma_f32_16x16x32_bf16(
                    a[m], b[j], acc[m][j], 0, 0, 0);
        __syncthreads();
    };

    for (int kt = 0; kt < NI * 32; kt += 32) {
        const unsigned short* Ap = (kt < D) ? A0 : A1;
        kstep(Ap, kt & (D - 1), kt, Wi, LDWI, accI);
    }
    for (int kt = 0; kt < D; kt += 32)
        kstep(Ah, kt, kt, Wh, D, accH);

    const int cr = (lane >> 4) * 4;
    const int cc = lane & 15;
    #pragma unroll
    for (int m = 0; m < 2; ++m) {
        #pragma unroll
        for (int jj = 0; jj < 2; ++jj) {
            const int col = c0 + jj * 16 + cc;
            const float bir = bi[col],       bhr = bh[col];
            const float biz = bi[col + 256], bhz = bh[col + 256];
            const float bin = bi[col + 512], bhn = bh[col + 512];
            #pragma unroll
            for (int q = 0; q < 4; ++q) {
                const int row = r0 + wid * 32 + m * 16 + cr + q;
                const float ir  = accI[m][jj][q]     + bir;
                const float hr  = accH[m][jj][q]     + bhr;
                const float iz  = accI[m][jj + 2][q] + biz;
                const float hz  = accH[m][jj + 2][q] + bhz;
                const float in_ = accI[m][jj + 4][q] + bin;
                const float hn  = accH[m][jj + 4][q] + bhn;
                const float rg = 1.f / (1.f + __expf(-(ir + hr)));
                const float zg = 1.f / (1.f + __expf(-(iz + hz)));
                const float ng = tanhf(in_ + rg * hn);
                const float hv  = hsrc[(size_t)row * 256 + col];
                out_f32[(size_t)row * 256 + col] = (1.f - zg) * ng + zg * hv;
            }
        }
    }
}

// ---------------------------------------------------------------------------
// Kernel 2: attention (1024 role-blocks, 4 b per block) || global GRU (256
// role-blocks, SAFE sync body). Role = bid%5: 0..3 attn, 4 GRU.
// The GRU runs "for free" under the HBM-bound attention phase.
// ---------------------------------------------------------------------------
__global__ __launch_bounds__(256) void attn_g(AttnGParams p)
{
    __shared__ unsigned short As[128 * 32];   // 8 KB  (GRU role only)
    __shared__ unsigned short Ws[128 * 32];   // 8 KB

    const int tid  = threadIdx.x;
    const int lane = tid & 63;
    const int wid  = tid >> 6;
    const int bid  = blockIdx.x;
    const int g5   = bid / 5;
    const int r5   = bid - g5 * 5;

    if (r5 == 4) {
        // global GRU tile g5 (0..255): x = [U | q0_sel], h = g_last -> g_out
        const int r0 = (g5 & 31) * 128, c0 = (g5 >> 5) * 32;
        gru_sync128<16, 512>(r0, c0, As, Ws, tid,
            p.U_bf, p.q0sel_bf, p.wgih_bf, p.bg_ih,
            p.glast_bf, p.wghh_bf, p.bg_hh,
            p.g_last, p.g_out);
        return;
    }

    // ---- attention: b = (g5*4 + r5)*4 + wid ----
    const int b = (g5 * 4 + r5) * 4 + wid;

    const float4 w4 = *reinterpret_cast<const float4*>(p.attn_w + lane * 4);
    const float* gbase = p.g_hist + (size_t)b * D + lane * 4;

    float  m = -INFINITY, l = 0.f;
    float4 acc = {0.f, 0.f, 0.f, 0.f};
    float  s0 = 0.f, s1 = 0.f;   // per-lane stash of raw scores (t&63==lane)

    auto step = [&](int t, const float4& g) {
        float dot = g.x * w4.x + g.y * w4.y + g.z * w4.z + g.w * w4.w;
        #pragma unroll
        for (int off = 32; off >= 1; off >>= 1)
            dot += __shfl_xor(dot, off, 64);
        const float mn   = fmaxf(m, dot);
        const float corr = __expf(m - mn);     // t==0: exp(-inf)=0 zeroes state
        const float pr   = __expf(dot - mn);
        l = l * corr + pr;
        acc.x = fmaf(pr, g.x, acc.x * corr);
        acc.y = fmaf(pr, g.y, acc.y * corr);
        acc.z = fmaf(pr, g.z, acc.z * corr);
        acc.w = fmaf(pr, g.w, acc.w * corr);
        m = mn;
        if ((t & 63) == lane) { if (t & 64) s1 = dot; else s0 = dot; }
    };

    for (int t = 0; t < T_N; t += 2) {
        const float4 g0 = *reinterpret_cast<const float4*>(gbase + (size_t)t * BD);
        const float4 g1 = *reinterpret_cast<const float4*>(gbase + (size_t)(t + 1) * BD);
        step(t, g0);
        step(t + 1, g1);
    }

    const float rl = 1.f / l;
    ushort4 cv = { f2bf(acc.x * rl), f2bf(acc.y * rl),
                   f2bf(acc.z * rl), f2bf(acc.w * rl) };
    *reinterpret_cast<ushort4*>(p.c_bf + (size_t)b * D + lane * 4) = cv;
    p.a_out[(size_t)b * T_N + lane]      = __expf(s0 - m) * rl;
    p.a_out[(size_t)b * T_N + 64 + lane] = __expf(s1 - m) * rl;
}

// ---------------------------------------------------------------------------
// Pipelined 64-row tile body (round-7 proven): 64 A-rows x 32 gate-cols,
// 4 waves each owning 16 rows x 96 cols; 3-deep pipeline, counted vmcnt
// (6/3/0). Defensive vmcnt(0) drain + sched_barrier(0) before the pipeline
// so the hand-counted base is exact regardless of codegen context.
//   MODE 0: out_f32[row*256+col] = val   (h = hsrc[row*256+col])
//   MODE 1: party — h = q0[row,qm,col]; writes q_out both slots + qs bf16
// ---------------------------------------------------------------------------
template<int MODE, int NI, int LDWI>
__device__ __forceinline__ void gru_body64(
    int r0, int c0, unsigned short* smem, int tid,
    const unsigned short* __restrict__ A0,
    const unsigned short* __restrict__ A1,
    const unsigned short* __restrict__ Wi, const float* __restrict__ bi,
    const unsigned short* __restrict__ Ah,
    const unsigned short* __restrict__ Wh, const float* __restrict__ bh,
    const float* __restrict__ hsrc, const int* __restrict__ qm,
    float* __restrict__ out_f32, unsigned short* __restrict__ out_bf)
{
    constexpr int NT = NI + 8;

    const int lane = tid & 63;
    const int wid  = tid >> 6;
    const int st_row = lane >> 2;
    const int st_p   = lane & 3;

    f32x4 accI[6] = {};
    f32x4 accH[6] = {};

    auto stage = [&](int step, int buf) {
        const unsigned short* Apart;
        const unsigned short* W;
        int kcolA, kcolW, ldw;
        if (step < NI) {
            const int kt = step * 32;
            Apart = (kt < D) ? A0 : A1;
            kcolA = kt & (D - 1);
            kcolW = kt;
            W     = Wi;
            ldw   = LDWI;
        } else {
            const int kt = (step - NI) * 32;
            Apart = Ah; kcolA = kt; kcolW = kt; W = Wh; ldw = D;
        }
        unsigned short* As = smem + buf * 6144;
        unsigned short* Ws = As + 2048;
        {
            const int row  = wid * 16 + st_row;
            const int scol = (st_p ^ ((row >> 1) & 3)) * 8;
            __builtin_amdgcn_global_load_lds(
                (const __attribute__((address_space(1))) void*)
                    (Apart + (size_t)(r0 + row) * D + kcolA + scol),
                (__attribute__((address_space(3))) void*)
                    (As + wid * 512), 16, 0, 0);
        }
        #pragma unroll
        for (int c = 0; c < 2; ++c) {
            const int row  = wid * 32 + c * 16 + st_row;
            const int scol = (st_p ^ ((row >> 1) & 3)) * 8;
            int grp = row >> 5; if (grp == 3) grp = 2;
            const int wrow = grp * 256 + c0 + (row & 31);
            __builtin_amdgcn_global_load_lds(
                (const __attribute__((address_space(1))) void*)
                    (W + (size_t)wrow * ldw + kcolW + scol),
                (__attribute__((address_space(3))) void*)
                    (Ws + wid * 1024 + c * 512), 16, 0, 0);
        }
    };

    auto compute = [&](int buf, f32x4 (&acc)[6]) {
        const unsigned short* As = smem + buf * 6144;
        const unsigned short* Ws = As + 2048;
        const int s  = lane >> 4;
        const int fr = lane & 15;
        bf16x8 a, b[6];
        {
            const int row = wid * 16 + fr;
            const int ph  = s ^ ((row >> 1) & 3);
            a = *reinterpret_cast<const bf16x8*>(&As[row * 32 + ph * 8]);
        }
        #pragma unroll
        for (int j = 0; j < 6; ++j) {
            const int row = j * 16 + fr;
            const int ph  = s ^ ((row >> 1) & 3);
            b[j] = *reinterpret_cast<const bf16x8*>(&Ws[row * 32 + ph * 8]);
        }
        #pragma unroll
        for (int j = 0; j < 6; ++j)
            acc[j] = __builtin_amdgcn_mfma_f32_16x16x32_bf16(
                a, b[j], acc[j], 0, 0, 0);
    };

    // defensive: zero outstanding vector ops before the counted pipeline
    asm volatile("s_waitcnt vmcnt(0)" ::: "memory");
    __builtin_amdgcn_sched_barrier(0);

    stage(0, 0);
    stage(1, 1);

    int cb = 0, ib = 2;
    for (int s = 0; s < NT; ++s) {
        if (s + 2 < NT) stage(s + 2, ib);
        const int rem = NT - 1 - s;
        if (rem >= 2)      asm volatile("s_waitcnt vmcnt(6)" ::: "memory");
        else if (rem == 1) asm volatile("s_waitcnt vmcnt(3)" ::: "memory");
        else               asm volatile("s_waitcnt vmcnt(0)" ::: "memory");
        __builtin_amdgcn_sched_barrier(0);
        __builtin_amdgcn_s_barrier();
        if (s < NI) compute(cb, accI);
        else        compute(cb, accH);
        __builtin_amdgcn_s_barrier();
        cb = (cb == 2) ? 0 : cb + 1;
        ib = (ib == 2) ? 0 : ib + 1;
    }
    __builtin_amdgcn_sched_barrier(0);

    const int cr = (lane >> 4) * 4;
    const int cc = lane & 15;
    #pragma unroll
    for (int jj = 0; jj < 2; ++jj) {
        const int col = c0 + jj * 16 + cc;
        const float bir = bi[col],       bhr = bh[col];
        const float biz = bi[col + 256], bhz = bh[col + 256];
        const float bin = bi[col + 512], bhn = bh[col + 512];
        #pragma unroll
        for (int q = 0; q < 4; ++q) {
            const int row = r0 + wid * 16 + cr + q;
            const float ir  = accI[jj][q]     + bir;
            const float hr  = accH[jj][q]     + bhr;
            const float iz  = accI[jj + 2][q] + biz;
            const float hz  = accH[jj + 2][q] + bhz;
            const float in_ = accI[jj + 4][q] + bin;
            const float hn  = accH[jj + 4][q] + bhn;
            const float rg = 1.f / (1.f + __expf(-(ir + hr)));
            const float zg = 1.f / (1.f + __expf(-(iz + hz)));
            const float ng = tanhf(in_ + rg * hn);
            if (MODE == 1) {
                const int p = qm[row];
                const float hv  = hsrc[(size_t)row * 512 + (size_t)p * 256 + col];
                const float ov  = hsrc[(size_t)row * 512 + (size_t)(1 - p) * 256 + col];
                const float val = (1.f - zg) * ng + zg * hv;
                out_f32[(size_t)row * 512 + (size_t)p * 256 + col]       = val;
                out_f32[(size_t)row * 512 + (size_t)(1 - p) * 256 + col] = ov;
                out_bf[(size_t)row * 256 + col] = f2bf(val);
            } else {
                const float hv  = hsrc[(size_t)row * 256 + col];
                const float val = (1.f - zg) * ng + zg * hv;
                out_f32[(size_t)row * 256 + col] = val;
            }
        }
    }
}

// ---------------------------------------------------------------------------
// Kernel 3: party GRU, 512 blocks of 64-row tiles (2 blocks/CU).
// ---------------------------------------------------------------------------
__global__ __launch_bounds__(256) void party_gru(
    const unsigned short* __restrict__ U_bf,
    const unsigned short* __restrict__ c_bf,
    const unsigned short* __restrict__ wpih_bf, const float* __restrict__ bp_ih,
    const unsigned short* __restrict__ q0sel_bf,
    const unsigned short* __restrict__ wphh_bf, const float* __restrict__ bp_hh,
    const float* __restrict__ q0, const int* __restrict__ qm,
    float* __restrict__ q_out, unsigned short* __restrict__ qssel_bf)
{
    __shared__ unsigned short smem[3 * 6144];
    const int bid = blockIdx.x;
    const int r0 = (bid & 63) * 64, c0 = (bid >> 6) * 32;
    gru_body64<1, 16, 512>(r0, c0, smem, threadIdx.x,
        U_bf, c_bf, wpih_bf, bp_ih,
        q0sel_bf, wphh_bf, bp_hh,
        q0, qm, q_out, qssel_bf);
}

// ---------------------------------------------------------------------------
// Kernel 4: emotion GRU, 512 blocks of 64-row tiles.
// ---------------------------------------------------------------------------
__global__ __launch_bounds__(256) void e_gru(
    const unsigned short* __restrict__ qssel_bf,
    const unsigned short* __restrict__ weih_bf, const float* __restrict__ be_ih,
    const unsigned short* __restrict__ e0_bf,
    const unsigned short* __restrict__ wehh_bf, const float* __restrict__ be_hh,
    const float* __restrict__ e0, float* __restrict__ e_out)
{
    __shared__ unsigned short smem[3 * 6144];
    const int bid = blockIdx.x;
    const int r0 = (bid & 63) * 64, c0 = (bid >> 6) * 32;
    gru_body64<0, 8, 256>(r0, c0, smem, threadIdx.x,
        qssel_bf, nullptr, weih_bf, be_ih,
        e0_bf, wehh_bf, be_hh,
        e0, nullptr, e_out, nullptr);
}

// ---------------------------------------------------------------------------
extern "C" void kernel_launch(void* const* d_in, const int* in_sizes, int n_in,
                              void* d_out, int out_size, void* d_ws, size_t ws_size,
                              hipStream_t stream)
{
    const float* U      = (const float*)d_in[0];
    const int*   qm     = (const int*)  d_in[1];
    const float* g_hist = (const float*)d_in[2];
    const float* q0     = (const float*)d_in[3];
    const float* e0     = (const float*)d_in[4];
    const float* wg_ih  = (const float*)d_in[5];
    const float* wg_hh  = (const float*)d_in[6];
    const float* bg_ih  = (const float*)d_in[7];
    const float* bg_hh  = (const float*)d_in[8];
    const float* wp_ih  = (const float*)d_in[9];
    const float* wp_hh  = (const float*)d_in[10];
    const float* bp_ih  = (const float*)d_in[11];
    const float* bp_hh  = (const float*)d_in[12];
    const float* we_ih  = (const float*)d_in[13];
    const float* we_hh  = (const float*)d_in[14];
    const float* be_ih  = (const float*)d_in[15];
    const float* be_hh  = (const float*)d_in[16];
    const float* attn_w = (const float*)d_in[17];

    float* out   = (float*)d_out;
    float* g_out = out;                       // [B, 256]
    float* q_out = out + 1048576;             // [B, 2, 256]
    float* e_out = out + 3145728;             // [B, 256]
    float* a_out = out + 4194304;             // [B, 1, 128]

    unsigned short* bf = (unsigned short*)d_ws;
    unsigned short* U_bf     = bf;
    unsigned short* e0_bf    = bf + 1048576;
    unsigned short* glast_bf = bf + 2097152;
    unsigned short* q0sel_bf = bf + 3145728;
    unsigned short* c_bf     = bf + 4194304;
    unsigned short* qssel_bf = bf + 5242880;
    unsigned short* wgih_bf  = bf + 6291456;
    unsigned short* wpih_bf  = bf + 6684672;
    unsigned short* wghh_bf  = bf + 7077888;
    unsigned short* wphh_bf  = bf + 7274496;
    unsigned short* weih_bf  = bf + 7471104;
    unsigned short* wehh_bf  = bf + 7667712;       // end 7864320 elems (15.7 MB)

    const float* g_last = g_hist + (size_t)(T_N - 1) * BD;

    CvtParams cp;
    cp.U = U; cp.e0 = e0; cp.g_last = g_last; cp.q0 = q0; cp.qm = qm;
    cp.wg_ih = wg_ih; cp.wg_hh = wg_hh; cp.wp_ih = wp_ih; cp.wp_hh = wp_hh;
    cp.we_ih = we_ih; cp.we_hh = we_hh;
    cp.U_bf = U_bf; cp.e0_bf = e0_bf; cp.glast_bf = glast_bf;
    cp.q0sel_bf = q0sel_bf;
    cp.wgih_bf = wgih_bf; cp.wpih_bf = wpih_bf; cp.wghh_bf = wghh_bf;
    cp.wphh_bf = wphh_bf; cp.weih_bf = weih_bf; cp.wehh_bf = wehh_bf;

    AttnGParams ag;
    ag.g_hist = g_hist; ag.attn_w = attn_w; ag.g_last = g_last;
    ag.a_out = a_out; ag.g_out = g_out; ag.c_bf = c_bf;
    ag.U_bf = U_bf; ag.q0sel_bf = q0sel_bf; ag.glast_bf = glast_bf;
    ag.wgih_bf = wgih_bf; ag.wghh_bf = wghh_bf;
    ag.bg_ih = bg_ih; ag.bg_hh = bg_hh;

    const dim3 blk(256);
    cvt_all<<<CGRID, blk, 0, stream>>>(cp);
    attn_g<<<1280, blk, 0, stream>>>(ag);
    party_gru<<<512, blk, 0, stream>>>(
        U_bf, c_bf, wpih_bf, bp_ih, q0sel_bf, wphh_bf, bp_hh,
        q0, qm, q_out, qssel_bf);
    e_gru<<<512, blk, 0, stream>>>(
        qssel_bf, weih_bf, be_ih, e0_bf, wehh_bf, be_hh, e0, e_out);
}

// Round 13
// 164.436 us; speedup vs baseline: 1.3484x; 1.3087x over previous
//
#include <hip/hip_runtime.h>
#include <hip/hip_bf16.h>
#include <cstdint>
#include <cstddef>

// Problem constants (DialogueRNNCell: B=4096, T=128, P=2, all feature dims 256)
#define B_N   4096
#define T_N   128
#define P_N   2
#define D     256
#define NG    768                  // 3*D gate width
#define BD    (B_N * D)            // elements per g_hist time slice
#define AGRID 1024                 // attn_fused grid
#define AGSIZE (AGRID * 256)

typedef __attribute__((ext_vector_type(4))) float f32x4;
typedef __attribute__((ext_vector_type(8))) short bf16x8;
typedef __attribute__((ext_vector_type(8))) unsigned short ushort8;

__device__ __forceinline__ unsigned short f2bf(float f) {
    __hip_bfloat16 h = __float2bfloat16(f);
    return *reinterpret_cast<unsigned short*>(&h);
}

// ---------------------------------------------------------------------------
// Params structs
// ---------------------------------------------------------------------------
struct AttnParams {
    const float *U, *g_hist, *q0, *e0;
    const int   *qm;
    const float *wg_ih, *wg_hh, *wp_ih, *wp_hh, *we_ih, *we_hh;
    const float *attn_w;
    float *a_out;
    unsigned short *U_bf, *e0_bf, *glast_bf, *q0sel_bf, *c_bf;
    unsigned short *wgih_bf, *wpih_bf, *wghh_bf, *wphh_bf, *weih_bf, *wehh_bf;
};

struct GPParams {
    const unsigned short *U_bf, *q0sel_bf, *glast_bf, *c_bf;
    const unsigned short *wgih_bf, *wghh_bf, *wpih_bf, *wphh_bf;
    const float *bg_ih, *bg_hh, *bp_ih, *bp_hh;
    const float *g_last, *q0;
    const int *qm;
    float *g_out, *q_out;
    unsigned short *qssel_bf;
};

// ---------------------------------------------------------------------------
// f32 -> bf16 grid-stride conversion, 8 elems per iteration
// ---------------------------------------------------------------------------
__device__ __forceinline__ void cvt8(
    const float* __restrict__ src, unsigned short* __restrict__ dst,
    int n8, int gtid)
{
    for (int i = gtid; i < n8; i += AGSIZE) {
        const float4* s = reinterpret_cast<const float4*>(src + i * 8);
        const float4 v0 = s[0], v1 = s[1];
        ushort8 o = { f2bf(v0.x), f2bf(v0.y), f2bf(v0.z), f2bf(v0.w),
                      f2bf(v1.x), f2bf(v1.y), f2bf(v1.z), f2bf(v1.w) };
        *reinterpret_cast<ushort8*>(dst + i * 8) = o;
    }
}

// ---------------------------------------------------------------------------
// Kernel 1: cvt + gather prelude (grid-stride) then attention.
// Attn: one wave per b, one pass, online softmax, t-loop unrolled x4
// (4 independent HBM loads in flight per dependent-chain segment).
// c_ emitted in bf16. Kernel completion = barrier before the GRUs.
// ---------------------------------------------------------------------------
__global__ __launch_bounds__(256) void attn_fused(AttnParams p)
{
    const int tid  = threadIdx.x;
    const int lane = tid & 63;
    const int wid  = tid >> 6;
    const int gtid = blockIdx.x * 256 + tid;

    const float* g_last = p.g_hist + (size_t)(T_N - 1) * BD;

    // ---- prelude: conversions + gather (grid-stride over whole grid) ----
    cvt8(p.wg_ih, p.wgih_bf, NG * 512 / 8, gtid);
    cvt8(p.wg_hh, p.wghh_bf, NG * 256 / 8, gtid);
    cvt8(p.wp_ih, p.wpih_bf, NG * 512 / 8, gtid);
    cvt8(p.wp_hh, p.wphh_bf, NG * 256 / 8, gtid);
    cvt8(p.we_ih, p.weih_bf, NG * 256 / 8, gtid);
    cvt8(p.we_hh, p.wehh_bf, NG * 256 / 8, gtid);
    cvt8(p.U,     p.U_bf,     B_N * D / 8, gtid);
    cvt8(p.e0,    p.e0_bf,    B_N * D / 8, gtid);
    cvt8(g_last,  p.glast_bf, B_N * D / 8, gtid);
    for (int i = gtid; i < B_N * D / 4; i += AGSIZE) {
        const int row = i >> 6;
        const int j   = (i & 63) * 4;
        const float4 v = *reinterpret_cast<const float4*>(
            p.q0 + ((size_t)row * P_N + p.qm[row]) * D + j);
        ushort4 bv = { f2bf(v.x), f2bf(v.y), f2bf(v.z), f2bf(v.w) };
        *reinterpret_cast<ushort4*>(p.q0sel_bf + (size_t)row * D + j) = bv;
    }

    // ---- attention: b = blockIdx.x*4 + wid ----
    const int b = blockIdx.x * 4 + wid;

    const float4 w4 = *reinterpret_cast<const float4*>(p.attn_w + lane * 4);
    const float* gbase = p.g_hist + (size_t)b * D + lane * 4;

    float  m = -INFINITY, l = 0.f;
    float4 acc = {0.f, 0.f, 0.f, 0.f};
    float  s0 = 0.f, s1 = 0.f;   // per-lane stash of raw scores (t&63==lane)

    auto step = [&](int t, const float4& g) {
        float dot = g.x * w4.x + g.y * w4.y + g.z * w4.z + g.w * w4.w;
        #pragma unroll
        for (int off = 32; off >= 1; off >>= 1)
            dot += __shfl_xor(dot, off, 64);
        const float mn   = fmaxf(m, dot);
        const float corr = __expf(m - mn);     // t==0: exp(-inf)=0 zeroes state
        const float pr   = __expf(dot - mn);
        l = l * corr + pr;
        acc.x = fmaf(pr, g.x, acc.x * corr);
        acc.y = fmaf(pr, g.y, acc.y * corr);
        acc.z = fmaf(pr, g.z, acc.z * corr);
        acc.w = fmaf(pr, g.w, acc.w * corr);
        m = mn;
        if ((t & 63) == lane) { if (t & 64) s1 = dot; else s0 = dot; }
    };

    for (int t = 0; t < T_N; t += 4) {
        const float4 ga = *reinterpret_cast<const float4*>(gbase + (size_t)t * BD);
        const float4 gb = *reinterpret_cast<const float4*>(gbase + (size_t)(t + 1) * BD);
        const float4 gc = *reinterpret_cast<const float4*>(gbase + (size_t)(t + 2) * BD);
        const float4 gd = *reinterpret_cast<const float4*>(gbase + (size_t)(t + 3) * BD);
        step(t,     ga);
        step(t + 1, gb);
        step(t + 2, gc);
        step(t + 3, gd);
    }

    const float rl = 1.f / l;
    ushort4 cv = { f2bf(acc.x * rl), f2bf(acc.y * rl),
                   f2bf(acc.z * rl), f2bf(acc.w * rl) };
    *reinterpret_cast<ushort4*>(p.c_bf + (size_t)b * D + lane * 4) = cv;
    p.a_out[(size_t)b * T_N + lane]      = __expf(s0 - m) * rl;
    p.a_out[(size_t)b * T_N + 64 + lane] = __expf(s1 - m) * rl;
}

// ---------------------------------------------------------------------------
// Fused GRU tile body, BK=64 double-buffered (halves barrier count vs r6):
// 128 A-rows x 32 gate-cols; W-tile = rows {c0,c0+256,c0+512}+32 padded
// 96->128 by duplication. 16x16x32 MFMA, 4 waves, 12 (big) / 8 (small)
// K-steps of 64. Staging: 8 calls/wave/step (4 A + 4 W), counted vmcnt(8)
// steady-state, vmcnt(0) only at the last step. LDS chunk row = 64 ush
// (8 slots of 16B); XOR swizzle phys_slot = sl ^ (row&7) applied on the
// global SOURCE (linear LDS dest) and on the ds_read side — bank =
// phys_slot*4 only, XOR spreads 64 lanes evenly over 32 banks.
// MFMA order per (row,col): kappa=0 then kappa=1 per step == two successive
// BK=32 steps -> bit-identical to the r6/r9 bodies.
// kcolA / kcolW SEPARATE (round-3 lesson).
//   MODE 0: out_f32[row*256+col] = val   (h = hsrc[row*256+col])
//   MODE 1: party — h = q0[row,qm,col]; writes q_out both slots + qs bf16
// ---------------------------------------------------------------------------
template<int MODE, int NI64, int LDWI>   // NI64 = input K-steps of 64
__device__ __forceinline__ void gru_body_k64(
    int r0, int c0, unsigned short* smem, int tid,
    const unsigned short* __restrict__ A0,
    const unsigned short* __restrict__ A1,
    const unsigned short* __restrict__ Wi, const float* __restrict__ bi,
    const unsigned short* __restrict__ Ah,
    const unsigned short* __restrict__ Wh, const float* __restrict__ bh,
    const float* __restrict__ hsrc, const int* __restrict__ qm,
    float* __restrict__ out_f32, unsigned short* __restrict__ out_bf)
{
    constexpr int NT = NI64 + 4;          // hidden K = 256 -> 4 steps of 64

    const int lane = tid & 63;
    const int wid  = tid >> 6;
    const int st_row = lane >> 3;         // 0..7 (row within 8-row call)
    const int st_p   = lane & 7;          // physical 16B slot 0..7

    f32x4 accI[2][6] = {};
    f32x4 accH[2][6] = {};

    // issue the 8 global_load_lds (4 A + 4 W) for step `step` into buffer
    auto stage = [&](int step, int buf) {
        const unsigned short* Apart;
        const unsigned short* W;
        int kcolA, kcolW, ldw;
        if (step < NI64) {
            const int kt = step * 64;
            Apart = (kt < D) ? A0 : A1;   // 64 | 256: no straddle
            kcolA = kt & (D - 1);
            kcolW = kt;
            W     = Wi;
            ldw   = LDWI;
        } else {
            const int kt = (step - NI64) * 64;
            Apart = Ah; kcolA = kt; kcolW = kt; W = Wh; ldw = D;
        }
        unsigned short* As = smem + buf * 16384;
        unsigned short* Ws = As + 8192;
        #pragma unroll
        for (int c = 0; c < 4; ++c) {
            const int row  = wid * 32 + c * 8 + st_row;       // 0..127
            const int scol = (st_p ^ (row & 7)) * 8;          // swizzled src
            __builtin_amdgcn_global_load_lds(
                (const __attribute__((address_space(1))) void*)
                    (Apart + (size_t)(r0 + row) * D + kcolA + scol),
                (__attribute__((address_space(3))) void*)
                    (As + (wid * 32 + c * 8) * 64), 16, 0, 0);
            int grp = row >> 5; if (grp == 3) grp = 2;        // pad rows dup
            const int wrow = grp * 256 + c0 + (row & 31);
            __builtin_amdgcn_global_load_lds(
                (const __attribute__((address_space(1))) void*)
                    (W + (size_t)wrow * ldw + kcolW + scol),
                (__attribute__((address_space(3))) void*)
                    (Ws + (wid * 32 + c * 8) * 64), 16, 0, 0);
        }
    };

    // ds_read fragments from buffer and accumulate 24 MFMAs (2 k-slices)
    auto compute = [&](int buf, f32x4 (&acc)[2][6]) {
        const unsigned short* As = smem + buf * 16384;
        const unsigned short* Ws = As + 8192;
        const int s  = lane >> 4;         // 0..3
        const int fr = lane & 15;
        #pragma unroll
        for (int kap = 0; kap < 2; ++kap) {
            const int sl = kap * 4 + s;   // logical slot 0..7
            bf16x8 a[2], b[6];
            #pragma unroll
            for (int m = 0; m < 2; ++m) {
                const int row = wid * 32 + m * 16 + fr;
                const int ph  = sl ^ (row & 7);
                a[m] = *reinterpret_cast<const bf16x8*>(&As[row * 64 + ph * 8]);
            }
            #pragma unroll
            for (int j = 0; j < 6; ++j) {
                const int row = j * 16 + fr;
                const int ph  = sl ^ (row & 7);
                b[j] = *reinterpret_cast<const bf16x8*>(&Ws[row * 64 + ph * 8]);
            }
            #pragma unroll
            for (int m = 0; m < 2; ++m)
                #pragma unroll
                for (int j = 0; j < 6; ++j)
                    acc[m][j] = __builtin_amdgcn_mfma_f32_16x16x32_bf16(
                        a[m], b[j], acc[m][j], 0, 0, 0);
        }
    };

    // defensive: known vmcnt base before the counted pipeline
    asm volatile("s_waitcnt vmcnt(0)" ::: "memory");
    __builtin_amdgcn_sched_barrier(0);

    stage(0, 0);
    stage(1, 1);

    for (int st = 0; st < NT; ++st) {
        if (st + 1 < NT) asm volatile("s_waitcnt vmcnt(8)" ::: "memory");
        else             asm volatile("s_waitcnt vmcnt(0)" ::: "memory");
        __builtin_amdgcn_sched_barrier(0);
        __builtin_amdgcn_s_barrier();        // all waves' step-st writes visible
        if (st < NI64) compute(st & 1, accI);
        else           compute(st & 1, accH);
        __builtin_amdgcn_s_barrier();        // reads done before buf rewrite
        if (st + 2 < NT) stage(st + 2, st & 1);
    }
    __builtin_amdgcn_sched_barrier(0);

    // ---- gate epilogue (thread-local: r/z/n fragments share (row,col)) ----
    const int cr = (lane >> 4) * 4;
    const int cc = lane & 15;
    #pragma unroll
    for (int m = 0; m < 2; ++m) {
        #pragma unroll
        for (int jj = 0; jj < 2; ++jj) {
            const int col = c0 + jj * 16 + cc;
            const float bir = bi[col],       bhr = bh[col];
            const float biz = bi[col + 256], bhz = bh[col + 256];
            const float bin = bi[col + 512], bhn = bh[col + 512];
            #pragma unroll
            for (int q = 0; q < 4; ++q) {
                const int row = r0 + wid * 32 + m * 16 + cr + q;
                const float ir  = accI[m][jj][q]     + bir;
                const float hr  = accH[m][jj][q]     + bhr;
                const float iz  = accI[m][jj + 2][q] + biz;
                const float hz  = accH[m][jj + 2][q] + bhz;
                const float in_ = accI[m][jj + 4][q] + bin;
                const float hn  = accH[m][jj + 4][q] + bhn;
                const float rg = 1.f / (1.f + __expf(-(ir + hr)));
                const float zg = 1.f / (1.f + __expf(-(iz + hz)));
                const float ng = tanhf(in_ + rg * hn);
                if (MODE == 1) {
                    const int p = qm[row];
                    const float hv  = hsrc[(size_t)row * 512 + (size_t)p * 256 + col];
                    const float ov  = hsrc[(size_t)row * 512 + (size_t)(1 - p) * 256 + col];
                    const float val = (1.f - zg) * ng + zg * hv;
                    out_f32[(size_t)row * 512 + (size_t)p * 256 + col]       = val;
                    out_f32[(size_t)row * 512 + (size_t)(1 - p) * 256 + col] = ov;
                    out_bf[(size_t)row * 256 + col] = f2bf(val);
                } else {
                    const float hv  = hsrc[(size_t)row * 256 + col];
                    const float val = (1.f - zg) * ng + zg * hv;
                    out_f32[(size_t)row * 256 + col] = val;
                }
            }
        }
    }
}

// ---------------------------------------------------------------------------
// Kernel 2: global GRU (blocks 0..255) | party GRU (blocks 256..511).
// 512 blocks, 64 KB LDS -> 2 blocks/CU cross-block latency hiding.
// ---------------------------------------------------------------------------
__global__ __launch_bounds__(256) void gp_gru(GPParams p)
{
    __shared__ unsigned short smem[2 * 16384];   // 64 KB
    const int tid = threadIdx.x;
    const int bid = blockIdx.x;

    if (bid < 256) {
        const int r0 = (bid & 31) * 128, c0 = (bid >> 5) * 32;
        gru_body_k64<0, 8, 512>(r0, c0, smem, tid,
            p.U_bf, p.q0sel_bf, p.wgih_bf, p.bg_ih,
            p.glast_bf, p.wghh_bf, p.bg_hh,
            p.g_last, nullptr, p.g_out, nullptr);
    } else {
        const int gb = bid - 256;
        const int r0 = (gb & 31) * 128, c0 = (gb >> 5) * 32;
        gru_body_k64<1, 8, 512>(r0, c0, smem, tid,
            p.U_bf, p.c_bf, p.wpih_bf, p.bp_ih,
            p.q0sel_bf, p.wphh_bf, p.bp_hh,
            p.q0, p.qm, p.q_out, p.qssel_bf);
    }
}

// ---------------------------------------------------------------------------
// Kernel 3: emotion GRU (256 blocks).
// ---------------------------------------------------------------------------
__global__ __launch_bounds__(256) void e_gru(
    const unsigned short* __restrict__ qssel_bf,
    const unsigned short* __restrict__ weih_bf, const float* __restrict__ be_ih,
    const unsigned short* __restrict__ e0_bf,
    const unsigned short* __restrict__ wehh_bf, const float* __restrict__ be_hh,
    const float* __restrict__ e0, float* __restrict__ e_out)
{
    __shared__ unsigned short smem[2 * 16384];
    const int tid = threadIdx.x;
    const int bid = blockIdx.x;
    const int r0 = (bid & 31) * 128, c0 = (bid >> 5) * 32;
    gru_body_k64<0, 4, 256>(r0, c0, smem, tid,
        qssel_bf, nullptr, weih_bf, be_ih,
        e0_bf, wehh_bf, be_hh,
        e0, nullptr, e_out, nullptr);
}

// ---------------------------------------------------------------------------
extern "C" void kernel_launch(void* const* d_in, const int* in_sizes, int n_in,
                              void* d_out, int out_size, void* d_ws, size_t ws_size,
                              hipStream_t stream)
{
    const float* U      = (const float*)d_in[0];
    const int*   qm     = (const int*)  d_in[1];
    const float* g_hist = (const float*)d_in[2];
    const float* q0     = (const float*)d_in[3];
    const float* e0     = (const float*)d_in[4];
    const float* wg_ih  = (const float*)d_in[5];
    const float* wg_hh  = (const float*)d_in[6];
    const float* bg_ih  = (const float*)d_in[7];
    const float* bg_hh  = (const float*)d_in[8];
    const float* wp_ih  = (const float*)d_in[9];
    const float* wp_hh  = (const float*)d_in[10];
    const float* bp_ih  = (const float*)d_in[11];
    const float* bp_hh  = (const float*)d_in[12];
    const float* we_ih  = (const float*)d_in[13];
    const float* we_hh  = (const float*)d_in[14];
    const float* be_ih  = (const float*)d_in[15];
    const float* be_hh  = (const float*)d_in[16];
    const float* attn_w = (const float*)d_in[17];

    float* out   = (float*)d_out;
    float* g_out = out;                       // [B, 256]
    float* q_out = out + 1048576;             // [B, 2, 256]
    float* e_out = out + 3145728;             // [B, 256]
    float* a_out = out + 4194304;             // [B, 1, 128]

    unsigned short* bf = (unsigned short*)d_ws;
    unsigned short* U_bf     = bf;
    unsigned short* e0_bf    = bf + 1048576;
    unsigned short* glast_bf = bf + 2097152;
    unsigned short* q0sel_bf = bf + 3145728;
    unsigned short* c_bf     = bf + 4194304;
    unsigned short* qssel_bf = bf + 5242880;
    unsigned short* wgih_bf  = bf + 6291456;
    unsigned short* wpih_bf  = bf + 6684672;
    unsigned short* wghh_bf  = bf + 7077888;
    unsigned short* wphh_bf  = bf + 7274496;
    unsigned short* weih_bf  = bf + 7471104;
    unsigned short* wehh_bf  = bf + 7667712;       // end 7864320 elems (15.7 MB)

    const float* g_last = g_hist + (size_t)(T_N - 1) * BD;

    AttnParams ap;
    ap.U = U; ap.g_hist = g_hist; ap.q0 = q0; ap.e0 = e0; ap.qm = qm;
    ap.wg_ih = wg_ih; ap.wg_hh = wg_hh; ap.wp_ih = wp_ih; ap.wp_hh = wp_hh;
    ap.we_ih = we_ih; ap.we_hh = we_hh; ap.attn_w = attn_w;
    ap.a_out = a_out;
    ap.U_bf = U_bf; ap.e0_bf = e0_bf; ap.glast_bf = glast_bf;
    ap.q0sel_bf = q0sel_bf; ap.c_bf = c_bf;
    ap.wgih_bf = wgih_bf; ap.wpih_bf = wpih_bf; ap.wghh_bf = wghh_bf;
    ap.wphh_bf = wphh_bf; ap.weih_bf = weih_bf; ap.wehh_bf = wehh_bf;

    GPParams gp;
    gp.U_bf = U_bf; gp.q0sel_bf = q0sel_bf; gp.glast_bf = glast_bf;
    gp.c_bf = c_bf;
    gp.wgih_bf = wgih_bf; gp.wghh_bf = wghh_bf;
    gp.wpih_bf = wpih_bf; gp.wphh_bf = wphh_bf;
    gp.bg_ih = bg_ih; gp.bg_hh = bg_hh; gp.bp_ih = bp_ih; gp.bp_hh = bp_hh;
    gp.g_last = g_last; gp.q0 = q0; gp.qm = qm;
    gp.g_out = g_out; gp.q_out = q_out; gp.qssel_bf = qssel_bf;

    const dim3 blk(256);
    attn_fused<<<AGRID, blk, 0, stream>>>(ap);
    gp_gru<<<512, blk, 0, stream>>>(gp);
    e_gru<<<256, blk, 0, stream>>>(
        qssel_bf, weih_bf, be_ih, e0_bf, wehh_bf, be_hh, e0, e_out);
}

// Round 14
// 159.880 us; speedup vs baseline: 1.3868x; 1.0285x over previous
//
#include <hip/hip_runtime.h>
#include <hip/hip_bf16.h>
#include <cstdint>
#include <cstddef>

// Problem constants (DialogueRNNCell: B=4096, T=128, P=2, all feature dims 256)
#define B_N   4096
#define T_N   128
#define P_N   2
#define D     256
#define NG    768                  // 3*D gate width
#define BD    (B_N * D)            // elements per g_hist time slice
#define AGRID 1024                 // attn_fused grid
#define AGSIZE (AGRID * 256)

typedef __attribute__((ext_vector_type(4))) float f32x4;
typedef __attribute__((ext_vector_type(8))) short bf16x8;
typedef __attribute__((ext_vector_type(8))) unsigned short ushort8;

__device__ __forceinline__ unsigned short f2bf(float f) {
    __hip_bfloat16 h = __float2bfloat16(f);
    return *reinterpret_cast<unsigned short*>(&h);
}

// ---------------------------------------------------------------------------
// Params structs
// ---------------------------------------------------------------------------
struct AttnParams {
    const float *U, *g_hist, *q0, *e0;
    const int   *qm;
    const float *wg_ih, *wg_hh, *wp_ih, *wp_hh, *we_ih, *we_hh;
    const float *attn_w;
    float *a_out;
    unsigned short *U_bf, *e0_bf, *glast_bf, *q0sel_bf, *c_bf;
    unsigned short *wgih_bf, *wpih_bf, *wghh_bf, *wphh_bf, *weih_bf, *wehh_bf;
};

struct GPParams {
    const unsigned short *U_bf, *q0sel_bf, *glast_bf, *c_bf;
    const unsigned short *wgih_bf, *wghh_bf, *wpih_bf, *wphh_bf;
    const float *bg_ih, *bg_hh, *bp_ih, *bp_hh;
    const float *g_last, *q0;
    const int *qm;
    float *g_out, *q_out;
    unsigned short *qssel_bf;
};

// ---------------------------------------------------------------------------
// f32 -> bf16 grid-stride conversion, 8 elems per iteration
// ---------------------------------------------------------------------------
__device__ __forceinline__ void cvt8(
    const float* __restrict__ src, unsigned short* __restrict__ dst,
    int n8, int gtid)
{
    for (int i = gtid; i < n8; i += AGSIZE) {
        const float4* s = reinterpret_cast<const float4*>(src + i * 8);
        const float4 v0 = s[0], v1 = s[1];
        ushort8 o = { f2bf(v0.x), f2bf(v0.y), f2bf(v0.z), f2bf(v0.w),
                      f2bf(v1.x), f2bf(v1.y), f2bf(v1.z), f2bf(v1.w) };
        *reinterpret_cast<ushort8*>(dst + i * 8) = o;
    }
}

// ---------------------------------------------------------------------------
// Kernel 1: cvt + gather prelude (grid-stride) then attention (r9 form).
// Attn: one wave per b, one pass, online softmax, t-loop unrolled x2.
// c_ emitted in bf16. Kernel completion = barrier before the GRUs.
// ---------------------------------------------------------------------------
__global__ __launch_bounds__(256) void attn_fused(AttnParams p)
{
    const int tid  = threadIdx.x;
    const int lane = tid & 63;
    const int wid  = tid >> 6;
    const int gtid = blockIdx.x * 256 + tid;

    const float* g_last = p.g_hist + (size_t)(T_N - 1) * BD;

    // ---- prelude: conversions + gather (grid-stride over whole grid) ----
    cvt8(p.wg_ih, p.wgih_bf, NG * 512 / 8, gtid);
    cvt8(p.wg_hh, p.wghh_bf, NG * 256 / 8, gtid);
    cvt8(p.wp_ih, p.wpih_bf, NG * 512 / 8, gtid);
    cvt8(p.wp_hh, p.wphh_bf, NG * 256 / 8, gtid);
    cvt8(p.we_ih, p.weih_bf, NG * 256 / 8, gtid);
    cvt8(p.we_hh, p.wehh_bf, NG * 256 / 8, gtid);
    cvt8(p.U,     p.U_bf,     B_N * D / 8, gtid);
    cvt8(p.e0,    p.e0_bf,    B_N * D / 8, gtid);
    cvt8(g_last,  p.glast_bf, B_N * D / 8, gtid);
    for (int i = gtid; i < B_N * D / 4; i += AGSIZE) {
        const int row = i >> 6;
        const int j   = (i & 63) * 4;
        const float4 v = *reinterpret_cast<const float4*>(
            p.q0 + ((size_t)row * P_N + p.qm[row]) * D + j);
        ushort4 bv = { f2bf(v.x), f2bf(v.y), f2bf(v.z), f2bf(v.w) };
        *reinterpret_cast<ushort4*>(p.q0sel_bf + (size_t)row * D + j) = bv;
    }

    // ---- attention: b = blockIdx.x*4 + wid ----
    const int b = blockIdx.x * 4 + wid;

    const float4 w4 = *reinterpret_cast<const float4*>(p.attn_w + lane * 4);
    const float* gbase = p.g_hist + (size_t)b * D + lane * 4;

    float  m = -INFINITY, l = 0.f;
    float4 acc = {0.f, 0.f, 0.f, 0.f};
    float  s0 = 0.f, s1 = 0.f;   // per-lane stash of raw scores (t&63==lane)

    auto step = [&](int t, const float4& g) {
        float dot = g.x * w4.x + g.y * w4.y + g.z * w4.z + g.w * w4.w;
        #pragma unroll
        for (int off = 32; off >= 1; off >>= 1)
            dot += __shfl_xor(dot, off, 64);
        const float mn   = fmaxf(m, dot);
        const float corr = __expf(m - mn);     // t==0: exp(-inf)=0 zeroes state
        const float pr   = __expf(dot - mn);
        l = l * corr + pr;
        acc.x = fmaf(pr, g.x, acc.x * corr);
        acc.y = fmaf(pr, g.y, acc.y * corr);
        acc.z = fmaf(pr, g.z, acc.z * corr);
        acc.w = fmaf(pr, g.w, acc.w * corr);
        m = mn;
        if ((t & 63) == lane) { if (t & 64) s1 = dot; else s0 = dot; }
    };

    for (int t = 0; t < T_N; t += 2) {
        const float4 g0 = *reinterpret_cast<const float4*>(gbase + (size_t)t * BD);
        const float4 g1 = *reinterpret_cast<const float4*>(gbase + (size_t)(t + 1) * BD);
        step(t, g0);
        step(t + 1, g1);
    }

    const float rl = 1.f / l;
    ushort4 cv = { f2bf(acc.x * rl), f2bf(acc.y * rl),
                   f2bf(acc.z * rl), f2bf(acc.w * rl) };
    *reinterpret_cast<ushort4*>(p.c_bf + (size_t)b * D + lane * 4) = cv;
    p.a_out[(size_t)b * T_N + lane]      = __expf(s0 - m) * rl;
    p.a_out[(size_t)b * T_N + 64 + lane] = __expf(s1 - m) * rl;
}

// ---------------------------------------------------------------------------
// Fused GRU tile body (r6/r9-proven): 128 A-rows x 32 gate-cols, BK=32,
// 16x16x32 MFMA, 4 waves, 3-deep pipelined global_load_lds staging with
// counted vmcnt (8/4/0); 16B-slot XOR swizzle phys = s ^ ((row>>1)&3)
// applied on the global SOURCE (linear LDS dest) and on the ds_read side.
// kcolA and kcolW SEPARATE (round-3 lesson). W-tile rows {c0,c0+256,c0+512}
// padded 96->128 by duplication. Defensive vmcnt(0) drain at entry.
//   MODE 0: out_f32[row*256+col] = val   (h = hsrc[row*256+col])
//   MODE 1: party — h = q0[row,qm,col]; writes q_out both slots + qs bf16
// ---------------------------------------------------------------------------
template<int MODE, int NI, int LDWI>
__device__ __forceinline__ void gru_body128(
    int r0, int c0, unsigned short* smem, int tid,
    const unsigned short* __restrict__ A0,
    const unsigned short* __restrict__ A1,
    const unsigned short* __restrict__ Wi, const float* __restrict__ bi,
    const unsigned short* __restrict__ Ah,
    const unsigned short* __restrict__ Wh, const float* __restrict__ bh,
    const float* __restrict__ hsrc, const int* __restrict__ qm,
    float* __restrict__ out_f32, unsigned short* __restrict__ out_bf)
{
    constexpr int NT = NI + 8;

    const int lane = tid & 63;
    const int wid  = tid >> 6;
    const int st_row = lane >> 2;
    const int st_p   = lane & 3;

    f32x4 accI[2][6] = {};
    f32x4 accH[2][6] = {};

    auto stage = [&](int step, int buf) {
        const unsigned short* Apart;
        const unsigned short* W;
        int kcolA, kcolW, ldw;
        if (step < NI) {
            const int kt = step * 32;
            Apart = (kt < D) ? A0 : A1;
            kcolA = kt & (D - 1);
            kcolW = kt;
            W     = Wi;
            ldw   = LDWI;
        } else {
            const int kt = (step - NI) * 32;
            Apart = Ah; kcolA = kt; kcolW = kt; W = Wh; ldw = D;
        }
        unsigned short* As = smem + buf * 8192;
        unsigned short* Ws = As + 4096;
        #pragma unroll
        for (int c = 0; c < 2; ++c) {
            const int row  = wid * 32 + c * 16 + st_row;          // 0..127
            const int scol = (st_p ^ ((row >> 1) & 3)) * 8;       // swizzled src
            __builtin_amdgcn_global_load_lds(
                (const __attribute__((address_space(1))) void*)
                    (Apart + (size_t)(r0 + row) * D + kcolA + scol),
                (__attribute__((address_space(3))) void*)
                    (As + wid * 1024 + c * 512), 16, 0, 0);
            int grp = row >> 5; if (grp == 3) grp = 2;            // pad rows dup
            const int wrow = grp * 256 + c0 + (row & 31);
            __builtin_amdgcn_global_load_lds(
                (const __attribute__((address_space(1))) void*)
                    (W + (size_t)wrow * ldw + kcolW + scol),
                (__attribute__((address_space(3))) void*)
                    (Ws + wid * 1024 + c * 512), 16, 0, 0);
        }
    };

    auto compute = [&](int buf, f32x4 (&acc)[2][6]) {
        const unsigned short* As = smem + buf * 8192;
        const unsigned short* Ws = As + 4096;
        const int s  = lane >> 4;
        const int fr = lane & 15;
        bf16x8 a[2], b[6];
        #pragma unroll
        for (int m = 0; m < 2; ++m) {
            const int row = wid * 32 + m * 16 + fr;
            const int ph  = s ^ ((row >> 1) & 3);
            a[m] = *reinterpret_cast<const bf16x8*>(&As[row * 32 + ph * 8]);
        }
        #pragma unroll
        for (int j = 0; j < 6; ++j) {
            const int row = j * 16 + fr;
            const int ph  = s ^ ((row >> 1) & 3);
            b[j] = *reinterpret_cast<const bf16x8*>(&Ws[row * 32 + ph * 8]);
        }
        #pragma unroll
        for (int m = 0; m < 2; ++m)
            #pragma unroll
            for (int j = 0; j < 6; ++j)
                acc[m][j] = __builtin_amdgcn_mfma_f32_16x16x32_bf16(
                    a[m], b[j], acc[m][j], 0, 0, 0);
    };

    // defensive: known vmcnt base before the counted pipeline
    asm volatile("s_waitcnt vmcnt(0)" ::: "memory");
    __builtin_amdgcn_sched_barrier(0);

    stage(0, 0);
    stage(1, 1);

    int cb = 0, ib = 2;
    for (int s = 0; s < NT; ++s) {
        if (s + 2 < NT) stage(s + 2, ib);
        const int rem = NT - 1 - s;
        if (rem >= 2)      asm volatile("s_waitcnt vmcnt(8)" ::: "memory");
        else if (rem == 1) asm volatile("s_waitcnt vmcnt(4)" ::: "memory");
        else               asm volatile("s_waitcnt vmcnt(0)" ::: "memory");
        __builtin_amdgcn_sched_barrier(0);
        __builtin_amdgcn_s_barrier();        // all waves' step-s writes visible
        if (s < NI) compute(cb, accI);
        else        compute(cb, accH);
        __builtin_amdgcn_s_barrier();        // reads done before buf rewrite
        cb = (cb == 2) ? 0 : cb + 1;
        ib = (ib == 2) ? 0 : ib + 1;
    }
    __builtin_amdgcn_sched_barrier(0);

    const int cr = (lane >> 4) * 4;
    const int cc = lane & 15;
    #pragma unroll
    for (int m = 0; m < 2; ++m) {
        #pragma unroll
        for (int jj = 0; jj < 2; ++jj) {
            const int col = c0 + jj * 16 + cc;
            const float bir = bi[col],       bhr = bh[col];
            const float biz = bi[col + 256], bhz = bh[col + 256];
            const float bin = bi[col + 512], bhn = bh[col + 512];
            #pragma unroll
            for (int q = 0; q < 4; ++q) {
                const int row = r0 + wid * 32 + m * 16 + cr + q;
                const float ir  = accI[m][jj][q]     + bir;
                const float hr  = accH[m][jj][q]     + bhr;
                const float iz  = accI[m][jj + 2][q] + biz;
                const float hz  = accH[m][jj + 2][q] + bhz;
                const float in_ = accI[m][jj + 4][q] + bin;
                const float hn  = accH[m][jj + 4][q] + bhn;
                const float rg = 1.f / (1.f + __expf(-(ir + hr)));
                const float zg = 1.f / (1.f + __expf(-(iz + hz)));
                const float ng = tanhf(in_ + rg * hn);
                if (MODE == 1) {
                    const int p = qm[row];
                    const float hv  = hsrc[(size_t)row * 512 + (size_t)p * 256 + col];
                    const float ov  = hsrc[(size_t)row * 512 + (size_t)(1 - p) * 256 + col];
                    const float val = (1.f - zg) * ng + zg * hv;
                    out_f32[(size_t)row * 512 + (size_t)p * 256 + col]       = val;
                    out_f32[(size_t)row * 512 + (size_t)(1 - p) * 256 + col] = ov;
                    out_bf[(size_t)row * 256 + col] = f2bf(val);
                } else {
                    const float hv  = hsrc[(size_t)row * 256 + col];
                    const float val = (1.f - zg) * ng + zg * hv;
                    out_f32[(size_t)row * 256 + col] = val;
                }
            }
        }
    }
}

// ---------------------------------------------------------------------------
// 64-row tile body (r7/r12-proven): 64 A-rows x 32 gate-cols, 4 waves each
// owning 16 rows x 96 cols; 3-deep pipeline, counted vmcnt (6/3/0),
// defensive entry drain. Same swizzle / kcol rules as above.
// ---------------------------------------------------------------------------
template<int MODE, int NI, int LDWI>
__device__ __forceinline__ void gru_body64(
    int r0, int c0, unsigned short* smem, int tid,
    const unsigned short* __restrict__ A0,
    const unsigned short* __restrict__ A1,
    const unsigned short* __restrict__ Wi, const float* __restrict__ bi,
    const unsigned short* __restrict__ Ah,
    const unsigned short* __restrict__ Wh, const float* __restrict__ bh,
    const float* __restrict__ hsrc, const int* __restrict__ qm,
    float* __restrict__ out_f32, unsigned short* __restrict__ out_bf)
{
    constexpr int NT = NI + 8;

    const int lane = tid & 63;
    const int wid  = tid >> 6;
    const int st_row = lane >> 2;
    const int st_p   = lane & 3;

    f32x4 accI[6] = {};
    f32x4 accH[6] = {};

    auto stage = [&](int step, int buf) {
        const unsigned short* Apart;
        const unsigned short* W;
        int kcolA, kcolW, ldw;
        if (step < NI) {
            const int kt = step * 32;
            Apart = (kt < D) ? A0 : A1;
            kcolA = kt & (D - 1);
            kcolW = kt;
            W     = Wi;
            ldw   = LDWI;
        } else {
            const int kt = (step - NI) * 32;
            Apart = Ah; kcolA = kt; kcolW = kt; W = Wh; ldw = D;
        }
        unsigned short* As = smem + buf * 6144;
        unsigned short* Ws = As + 2048;
        {
            const int row  = wid * 16 + st_row;
            const int scol = (st_p ^ ((row >> 1) & 3)) * 8;
            __builtin_amdgcn_global_load_lds(
                (const __attribute__((address_space(1))) void*)
                    (Apart + (size_t)(r0 + row) * D + kcolA + scol),
                (__attribute__((address_space(3))) void*)
                    (As + wid * 512), 16, 0, 0);
        }
        #pragma unroll
        for (int c = 0; c < 2; ++c) {
            const int row  = wid * 32 + c * 16 + st_row;
            const int scol = (st_p ^ ((row >> 1) & 3)) * 8;
            int grp = row >> 5; if (grp == 3) grp = 2;
            const int wrow = grp * 256 + c0 + (row & 31);
            __builtin_amdgcn_global_load_lds(
                (const __attribute__((address_space(1))) void*)
                    (W + (size_t)wrow * ldw + kcolW + scol),
                (__attribute__((address_space(3))) void*)
                    (Ws + wid * 1024 + c * 512), 16, 0, 0);
        }
    };

    auto compute = [&](int buf, f32x4 (&acc)[6]) {
        const unsigned short* As = smem + buf * 6144;
        const unsigned short* Ws = As + 2048;
        const int s  = lane >> 4;
        const int fr = lane & 15;
        bf16x8 a, b[6];
        {
            const int row = wid * 16 + fr;
            const int ph  = s ^ ((row >> 1) & 3);
            a = *reinterpret_cast<const bf16x8*>(&As[row * 32 + ph * 8]);
        }
        #pragma unroll
        for (int j = 0; j < 6; ++j) {
            const int row = j * 16 + fr;
            const int ph  = s ^ ((row >> 1) & 3);
            b[j] = *reinterpret_cast<const bf16x8*>(&Ws[row * 32 + ph * 8]);
        }
        #pragma unroll
        for (int j = 0; j < 6; ++j)
            acc[j] = __builtin_amdgcn_mfma_f32_16x16x32_bf16(
                a, b[j], acc[j], 0, 0, 0);
    };

    asm volatile("s_waitcnt vmcnt(0)" ::: "memory");
    __builtin_amdgcn_sched_barrier(0);

    stage(0, 0);
    stage(1, 1);

    int cb = 0, ib = 2;
    for (int s = 0; s < NT; ++s) {
        if (s + 2 < NT) stage(s + 2, ib);
        const int rem = NT - 1 - s;
        if (rem >= 2)      asm volatile("s_waitcnt vmcnt(6)" ::: "memory");
        else if (rem == 1) asm volatile("s_waitcnt vmcnt(3)" ::: "memory");
        else               asm volatile("s_waitcnt vmcnt(0)" ::: "memory");
        __builtin_amdgcn_sched_barrier(0);
        __builtin_amdgcn_s_barrier();
        if (s < NI) compute(cb, accI);
        else        compute(cb, accH);
        __builtin_amdgcn_s_barrier();
        cb = (cb == 2) ? 0 : cb + 1;
        ib = (ib == 2) ? 0 : ib + 1;
    }
    __builtin_amdgcn_sched_barrier(0);

    const int cr = (lane >> 4) * 4;
    const int cc = lane & 15;
    #pragma unroll
    for (int jj = 0; jj < 2; ++jj) {
        const int col = c0 + jj * 16 + cc;
        const float bir = bi[col],       bhr = bh[col];
        const float biz = bi[col + 256], bhz = bh[col + 256];
        const float bin = bi[col + 512], bhn = bh[col + 512];
        #pragma unroll
        for (int q = 0; q < 4; ++q) {
            const int row = r0 + wid * 16 + cr + q;
            const float ir  = accI[jj][q]     + bir;
            const float hr  = accH[jj][q]     + bhr;
            const float iz  = accI[jj + 2][q] + biz;
            const float hz  = accH[jj + 2][q] + bhz;
            const float in_ = accI[jj + 4][q] + bin;
            const float hn  = accH[jj + 4][q] + bhn;
            const float rg = 1.f / (1.f + __expf(-(ir + hr)));
            const float zg = 1.f / (1.f + __expf(-(iz + hz)));
            const float ng = tanhf(in_ + rg * hn);
            if (MODE == 1) {
                const int p = qm[row];
                const float hv  = hsrc[(size_t)row * 512 + (size_t)p * 256 + col];
                const float ov  = hsrc[(size_t)row * 512 + (size_t)(1 - p) * 256 + col];
                const float val = (1.f - zg) * ng + zg * hv;
                out_f32[(size_t)row * 512 + (size_t)p * 256 + col]       = val;
                out_f32[(size_t)row * 512 + (size_t)(1 - p) * 256 + col] = ov;
                out_bf[(size_t)row * 256 + col] = f2bf(val);
            } else {
                const float hv  = hsrc[(size_t)row * 256 + col];
                const float val = (1.f - zg) * ng + zg * hv;
                out_f32[(size_t)row * 256 + col] = val;
            }
        }
    }
}

// ---------------------------------------------------------------------------
// Kernel 2: global GRU (blocks 0..255) | party GRU (blocks 256..511).
// 512 blocks, 48 KB LDS -> 2 blocks/CU cross-block latency hiding. (r9)
// ---------------------------------------------------------------------------
__global__ __launch_bounds__(256) void gp_gru(GPParams p)
{
    __shared__ unsigned short smem[3 * 8192];   // 48 KB
    const int tid = threadIdx.x;
    const int bid = blockIdx.x;

    if (bid < 256) {
        const int r0 = (bid & 31) * 128, c0 = (bid >> 5) * 32;
        gru_body128<0, 16, 512>(r0, c0, smem, tid,
            p.U_bf, p.q0sel_bf, p.wgih_bf, p.bg_ih,
            p.glast_bf, p.wghh_bf, p.bg_hh,
            p.g_last, nullptr, p.g_out, nullptr);
    } else {
        const int gb = bid - 256;
        const int r0 = (gb & 31) * 128, c0 = (gb >> 5) * 32;
        gru_body128<1, 16, 512>(r0, c0, smem, tid,
            p.U_bf, p.c_bf, p.wpih_bf, p.bp_ih,
            p.q0sel_bf, p.wphh_bf, p.bp_hh,
            p.q0, p.qm, p.q_out, p.qssel_bf);
    }
}

// ---------------------------------------------------------------------------
// Kernel 3: emotion GRU, 512 blocks of 64-row tiles (2+ blocks/CU TLP).
// ---------------------------------------------------------------------------
__global__ __launch_bounds__(256) void e_gru(
    const unsigned short* __restrict__ qssel_bf,
    const unsigned short* __restrict__ weih_bf, const float* __restrict__ be_ih,
    const unsigned short* __restrict__ e0_bf,
    const unsigned short* __restrict__ wehh_bf, const float* __restrict__ be_hh,
    const float* __restrict__ e0, float* __restrict__ e_out)
{
    __shared__ unsigned short smem[3 * 6144];   // 36 KB
    const int bid = blockIdx.x;
    const int r0 = (bid & 63) * 64, c0 = (bid >> 6) * 32;
    gru_body64<0, 8, 256>(r0, c0, smem, threadIdx.x,
        qssel_bf, nullptr, weih_bf, be_ih,
        e0_bf, wehh_bf, be_hh,
        e0, nullptr, e_out, nullptr);
}

// ---------------------------------------------------------------------------
extern "C" void kernel_launch(void* const* d_in, const int* in_sizes, int n_in,
                              void* d_out, int out_size, void* d_ws, size_t ws_size,
                              hipStream_t stream)
{
    const float* U      = (const float*)d_in[0];
    const int*   qm     = (const int*)  d_in[1];
    const float* g_hist = (const float*)d_in[2];
    const float* q0     = (const float*)d_in[3];
    const float* e0     = (const float*)d_in[4];
    const float* wg_ih  = (const float*)d_in[5];
    const float* wg_hh  = (const float*)d_in[6];
    const float* bg_ih  = (const float*)d_in[7];
    const float* bg_hh  = (const float*)d_in[8];
    const float* wp_ih  = (const float*)d_in[9];
    const float* wp_hh  = (const float*)d_in[10];
    const float* bp_ih  = (const float*)d_in[11];
    const float* bp_hh  = (const float*)d_in[12];
    const float* we_ih  = (const float*)d_in[13];
    const float* we_hh  = (const float*)d_in[14];
    const float* be_ih  = (const float*)d_in[15];
    const float* be_hh  = (const float*)d_in[16];
    const float* attn_w = (const float*)d_in[17];

    float* out   = (float*)d_out;
    float* g_out = out;                       // [B, 256]
    float* q_out = out + 1048576;             // [B, 2, 256]
    float* e_out = out + 3145728;             // [B, 256]
    float* a_out = out + 4194304;             // [B, 1, 128]

    unsigned short* bf = (unsigned short*)d_ws;
    unsigned short* U_bf     = bf;
    unsigned short* e0_bf    = bf + 1048576;
    unsigned short* glast_bf = bf + 2097152;
    unsigned short* q0sel_bf = bf + 3145728;
    unsigned short* c_bf     = bf + 4194304;
    unsigned short* qssel_bf = bf + 5242880;
    unsigned short* wgih_bf  = bf + 6291456;
    unsigned short* wpih_bf  = bf + 6684672;
    unsigned short* wghh_bf  = bf + 7077888;
    unsigned short* wphh_bf  = bf + 7274496;
    unsigned short* weih_bf  = bf + 7471104;
    unsigned short* wehh_bf  = bf + 7667712;       // end 7864320 elems (15.7 MB)

    const float* g_last = g_hist + (size_t)(T_N - 1) * BD;

    AttnParams ap;
    ap.U = U; ap.g_hist = g_hist; ap.q0 = q0; ap.e0 = e0; ap.qm = qm;
    ap.wg_ih = wg_ih; ap.wg_hh = wg_hh; ap.wp_ih = wp_ih; ap.wp_hh = wp_hh;
    ap.we_ih = we_ih; ap.we_hh = we_hh; ap.attn_w = attn_w;
    ap.a_out = a_out;
    ap.U_bf = U_bf; ap.e0_bf = e0_bf; ap.glast_bf = glast_bf;
    ap.q0sel_bf = q0sel_bf; ap.c_bf = c_bf;
    ap.wgih_bf = wgih_bf; ap.wpih_bf = wpih_bf; ap.wghh_bf = wghh_bf;
    ap.wphh_bf = wphh_bf; ap.weih_bf = weih_bf; ap.wehh_bf = wehh_bf;

    GPParams gp;
    gp.U_bf = U_bf; gp.q0sel_bf = q0sel_bf; gp.glast_bf = glast_bf;
    gp.c_bf = c_bf;
    gp.wgih_bf = wgih_bf; gp.wghh_bf = wghh_bf;
    gp.wpih_bf = wpih_bf; gp.wphh_bf = wphh_bf;
    gp.bg_ih = bg_ih; gp.bg_hh = bg_hh; gp.bp_ih = bp_ih; gp.bp_hh = bp_hh;
    gp.g_last = g_last; gp.q0 = q0; gp.qm = qm;
    gp.g_out = g_out; gp.q_out = q_out; gp.qssel_bf = qssel_bf;

    const dim3 blk(256);
    attn_fused<<<AGRID, blk, 0, stream>>>(ap);
    gp_gru<<<512, blk, 0, stream>>>(gp);
    e_gru<<<512, blk, 0, stream>>>(
        qssel_bf, weih_bf, be_ih, e0_bf, wehh_bf, be_hh, e0, e_out);
}